// Round 2
// baseline (1919.784 us; speedup 1.0000x reference)
//
#include <hip/hip_runtime.h>

#define N_NODES 50000
#define C1 64    // in channels
#define C2 128   // hidden
#define C3 64    // latent / out

// ---------------- degree / norm ----------------
__global__ void k_init_deg(float* __restrict__ deg, float* __restrict__ stats) {
    int i = blockIdx.x * blockDim.x + threadIdx.x;
    if (i < N_NODES) deg[i] = 1.0f;          // self loop
    if (i < 512) stats[i] = 0.0f;            // sum/sumsq/scale/shift
}

__global__ void k_deg(const int* __restrict__ dst, int E, float* __restrict__ deg) {
    int i = blockIdx.x * blockDim.x + threadIdx.x;
    if (i < E) unsafeAtomicAdd(&deg[dst[i]], 1.0f);
}

__global__ void k_dinv(float* __restrict__ deg) {
    int i = blockIdx.x * blockDim.x + threadIdx.x;
    if (i < N_NODES) deg[i] = rsqrtf(deg[i]);   // deg >= 1 always
}

// ---------------- GEMM1: h1 = x @ W1 ----------------
__global__ __launch_bounds__(256) void k_gemm1(const float* __restrict__ x,
                                               const float* __restrict__ W1,
                                               float* __restrict__ h1) {
    __shared__ float Ws[C1 * C2];   // 64*128 = 32 KB
    __shared__ float Xs[32 * C1];   // 32*64  =  8 KB
    int tid = threadIdx.x;
    int r0 = blockIdx.x * 32;
    for (int i = tid; i < C1 * C2; i += 256) Ws[i] = W1[i];
    for (int i = tid; i < 32 * C1; i += 256) {
        int row = r0 + (i >> 6);
        Xs[i] = (row < N_NODES) ? x[row * C1 + (i & 63)] : 0.0f;
    }
    __syncthreads();
    int c = tid & 127;
    int rg = tid >> 7;  // 0..1, 16 rows each
    float acc[16];
#pragma unroll
    for (int r = 0; r < 16; ++r) acc[r] = 0.0f;
    for (int k = 0; k < C1; ++k) {
        float w = Ws[k * C2 + c];
#pragma unroll
        for (int r = 0; r < 16; ++r)
            acc[r] = fmaf(Xs[(rg * 16 + r) * C1 + k], w, acc[r]);
    }
#pragma unroll
    for (int r = 0; r < 16; ++r) {
        int row = r0 + rg * 16 + r;
        if (row < N_NODES) h1[row * C2 + c] = acc[r];
    }
}

// ---------------- self-loop init: agg1 = h1 * dinv^2 + b1 ----------------
__global__ void k_self1(const float* __restrict__ h1, const float* __restrict__ dinv,
                        const float* __restrict__ b1, float* __restrict__ agg1) {
    int i = blockIdx.x * blockDim.x + threadIdx.x;   // N*C2/4 threads
    if (i >= N_NODES * C2 / 4) return;
    int base = i * 4;
    int row = base >> 7;
    int c = base & 127;
    float di = dinv[row];
    float n = di * di;
    float4 v = *(const float4*)(h1 + base);
    float4 b = *(const float4*)(b1 + c);
    float4 o;
    o.x = fmaf(v.x, n, b.x); o.y = fmaf(v.y, n, b.y);
    o.z = fmaf(v.z, n, b.z); o.w = fmaf(v.w, n, b.w);
    *(float4*)(agg1 + base) = o;
}

// ---------------- edge scatter, layer 1 (128 ch): one wave per edge ----------------
__global__ __launch_bounds__(256) void k_scatter1(const int* __restrict__ src,
                                                  const int* __restrict__ dst,
                                                  const float* __restrict__ h1,
                                                  const float* __restrict__ dinv,
                                                  float* __restrict__ agg1, int E) {
    int e = blockIdx.x * 4 + (threadIdx.x >> 6);
    if (e >= E) return;
    int lane = threadIdx.x & 63;
    int s = src[e], d = dst[e];
    float nrm = dinv[s] * dinv[d];
    float2 v = *(const float2*)(h1 + s * C2 + lane * 2);
    unsafeAtomicAdd(&agg1[d * C2 + lane * 2],     v.x * nrm);
    unsafeAtomicAdd(&agg1[d * C2 + lane * 2 + 1], v.y * nrm);
}

// ---------------- BN stats: per-channel sum, sumsq ----------------
__global__ __launch_bounds__(256) void k_stats(const float* __restrict__ agg1,
                                               float* __restrict__ stats) {
    __shared__ float ls[256], lq[256];
    int tid = threadIdx.x;
    int c = tid & 127, half = tid >> 7;
    float s = 0.0f, q = 0.0f;
    for (int row = blockIdx.x * 2 + half; row < N_NODES; row += gridDim.x * 2) {
        float v = agg1[row * C2 + c];
        s += v; q += v * v;
    }
    ls[tid] = s; lq[tid] = q;
    __syncthreads();
    if (tid < 128) {
        s = ls[tid] + ls[tid + 128];
        q = lq[tid] + lq[tid + 128];
        unsafeAtomicAdd(&stats[c], s);
        unsafeAtomicAdd(&stats[128 + c], q);
    }
}

// ---------------- BN params: scale/shift ----------------
__global__ void k_bnparam(const float* __restrict__ gamma, const float* __restrict__ beta,
                          float* __restrict__ stats) {
    int c = threadIdx.x;
    if (c < 128) {
        const float invN = 1.0f / (float)N_NODES;
        float mean = stats[c] * invN;
        float var = stats[128 + c] * invN - mean * mean;
        float sc = gamma[c] * rsqrtf(var + 1e-5f);
        stats[256 + c] = sc;
        stats[384 + c] = beta[c] - mean * sc;
    }
}

// ---------------- GEMM2: h2 = relu(bn(agg1)) @ W2 (BN+ReLU fused on load) ----------------
__global__ __launch_bounds__(256) void k_gemm2(const float* __restrict__ agg1,
                                               const float* __restrict__ W2,
                                               const float* __restrict__ stats,
                                               float* __restrict__ h2) {
    __shared__ float Ws[C2 * C3];   // 128*64 = 32 KB
    __shared__ float As[32 * C2];   // 32*128 = 16 KB
    int tid = threadIdx.x;
    int r0 = blockIdx.x * 32;
    for (int i = tid; i < C2 * C3; i += 256) Ws[i] = W2[i];
    for (int i = tid; i < 32 * C2; i += 256) {
        int row = r0 + (i >> 7);
        int cc = i & 127;
        float v = 0.0f;
        if (row < N_NODES)
            v = fmaxf(fmaf(agg1[row * C2 + cc], stats[256 + cc], stats[384 + cc]), 0.0f);
        As[i] = v;
    }
    __syncthreads();
    int c = tid & 63;
    int rg = tid >> 6;  // 0..3, 8 rows each
    float acc[8];
#pragma unroll
    for (int r = 0; r < 8; ++r) acc[r] = 0.0f;
    for (int k = 0; k < C2; ++k) {
        float w = Ws[k * C3 + c];
#pragma unroll
        for (int r = 0; r < 8; ++r)
            acc[r] = fmaf(As[(rg * 8 + r) * C2 + k], w, acc[r]);
    }
#pragma unroll
    for (int r = 0; r < 8; ++r) {
        int row = r0 + rg * 8 + r;
        if (row < N_NODES) h2[row * C3 + c] = acc[r];
    }
}

// ---------------- self-loop init layer 2: out = h2 * dinv^2 + b2 ----------------
__global__ void k_self2(const float* __restrict__ h2, const float* __restrict__ dinv,
                        const float* __restrict__ b2, float* __restrict__ out) {
    int i = blockIdx.x * blockDim.x + threadIdx.x;   // N*C3/4 threads
    if (i >= N_NODES * C3 / 4) return;
    int base = i * 4;
    int row = base >> 6;
    int c = base & 63;
    float di = dinv[row];
    float n = di * di;
    float4 v = *(const float4*)(h2 + base);
    float4 b = *(const float4*)(b2 + c);
    float4 o;
    o.x = fmaf(v.x, n, b.x); o.y = fmaf(v.y, n, b.y);
    o.z = fmaf(v.z, n, b.z); o.w = fmaf(v.w, n, b.w);
    *(float4*)(out + base) = o;
}

// ---------------- edge scatter, layer 2 (64 ch): one wave per edge ----------------
__global__ __launch_bounds__(256) void k_scatter2(const int* __restrict__ src,
                                                  const int* __restrict__ dst,
                                                  const float* __restrict__ h2,
                                                  const float* __restrict__ dinv,
                                                  float* __restrict__ out, int E) {
    int e = blockIdx.x * 4 + (threadIdx.x >> 6);
    if (e >= E) return;
    int lane = threadIdx.x & 63;
    int s = src[e], d = dst[e];
    float nrm = dinv[s] * dinv[d];
    float v = h2[s * C3 + lane];
    unsafeAtomicAdd(&out[d * C3 + lane], v * nrm);
}

extern "C" void kernel_launch(void* const* d_in, const int* in_sizes, int n_in,
                              void* d_out, int out_size, void* d_ws, size_t ws_size,
                              hipStream_t stream) {
    const float* x     = (const float*)d_in[0];
    const int*   ei    = (const int*)d_in[1];
    const float* W1    = (const float*)d_in[2];
    const float* b1    = (const float*)d_in[3];
    const float* gamma = (const float*)d_in[4];
    const float* beta  = (const float*)d_in[5];
    const float* W2    = (const float*)d_in[6];
    const float* b2    = (const float*)d_in[7];
    float* out = (float*)d_out;

    int E = in_sizes[1] / 2;
    const int* src = ei;
    const int* dst = ei + E;

    // workspace layout (bytes):
    //   [0, 200704)              deg -> dinv (50000 floats, padded)
    //   [200704, 202752)         stats: sum[128] sumsq[128] scale[128] shift[128]
    //   [202752, +25.6MB)        h1 (50000x128) -- later reused as h2 (50000x64)
    //   [25802752, +25.6MB)      agg1 (50000x128)
    char* ws = (char*)d_ws;
    float* deg   = (float*)ws;
    float* stats = (float*)(ws + 200704);
    float* h1    = (float*)(ws + 202752);
    float* agg1  = (float*)(ws + 25802752);
    float* h2    = h1;   // h1 dead after k_scatter1

    const int nblk_nodes = (N_NODES + 255) / 256;          // 196
    const int nblk_rows  = (N_NODES + 31) / 32;            // 1563
    const int nblk_edge  = (E + 255) / 256;
    const int nblk_scat  = (E + 3) / 4;

    k_init_deg<<<nblk_nodes, 256, 0, stream>>>(deg, stats);
    k_deg<<<nblk_edge, 256, 0, stream>>>(dst, E, deg);
    k_dinv<<<nblk_nodes, 256, 0, stream>>>(deg);

    k_gemm1<<<nblk_rows, 256, 0, stream>>>(x, W1, h1);
    k_self1<<<(N_NODES * C2 / 4 + 255) / 256, 256, 0, stream>>>(h1, deg, b1, agg1);
    k_scatter1<<<nblk_scat, 256, 0, stream>>>(src, dst, h1, deg, agg1, E);

    k_stats<<<256, 256, 0, stream>>>(agg1, stats);
    k_bnparam<<<1, 128, 0, stream>>>(gamma, beta, stats);

    k_gemm2<<<nblk_rows, 256, 0, stream>>>(agg1, W2, stats, h2);
    k_self2<<<(N_NODES * C3 / 4 + 255) / 256, 256, 0, stream>>>(h2, deg, b2, out);
    k_scatter2<<<nblk_scat, 256, 0, stream>>>(src, dst, h2, deg, out, E);
}

// Round 3
// 716.802 us; speedup vs baseline: 2.6783x; 2.6783x over previous
//
#include <hip/hip_runtime.h>

#define N_NODES 50000
#define C1 64    // in channels
#define C2 128   // hidden
#define C3 64    // latent / out
#define SCAN_T 1024
#define CHUNK 49  // SCAN_T * CHUNK = 50176 >= N_NODES

// ---------------- zero indeg + stats ----------------
__global__ void k_zero(int* __restrict__ indeg, float* __restrict__ stats) {
    int i = blockIdx.x * blockDim.x + threadIdx.x;
    if (i < N_NODES) indeg[i] = 0;
    if (i < 512) stats[i] = 0.0f;
}

// ---------------- in-degree count (int atomics) ----------------
__global__ void k_deg(const int* __restrict__ dst, int E, int* __restrict__ indeg) {
    int i = blockIdx.x * blockDim.x + threadIdx.x;
    if (i < E) atomicAdd(&indeg[dst[i]], 1);
}

// ---------------- single-block scan: rowptr (exclusive), cursor copy, dinv ----------------
__global__ __launch_bounds__(SCAN_T) void k_scan(const int* __restrict__ indeg,
                                                 float* __restrict__ dinv,
                                                 int* __restrict__ rowptr,
                                                 int* __restrict__ cursor) {
    __shared__ int sums[SCAN_T];
    int t = threadIdx.x;
    int base = t * CHUNK;
    int s = 0;
    for (int k = 0; k < CHUNK; ++k) {
        int i = base + k;
        if (i < N_NODES) s += indeg[i];
    }
    sums[t] = s;
    __syncthreads();
    for (int off = 1; off < SCAN_T; off <<= 1) {
        int v = (t >= off) ? sums[t - off] : 0;
        __syncthreads();
        sums[t] += v;
        __syncthreads();
    }
    int run = sums[t] - s;  // exclusive prefix
    for (int k = 0; k < CHUNK; ++k) {
        int i = base + k;
        if (i < N_NODES) {
            int dg = indeg[i];
            rowptr[i] = run;
            cursor[i] = run;
            dinv[i] = rsqrtf(1.0f + (float)dg);   // deg includes self-loop
            run += dg;
        }
    }
    if (t == SCAN_T - 1) rowptr[N_NODES] = sums[t];
}

// ---------------- bucket edges into dst-CSR ----------------
__global__ void k_bucket(const int* __restrict__ src, const int* __restrict__ dst, int E,
                         int* __restrict__ cursor, int* __restrict__ csr) {
    int e = blockIdx.x * blockDim.x + threadIdx.x;
    if (e < E) {
        int d = dst[e];
        int pos = atomicAdd(&cursor[d], 1);
        csr[pos] = src[e];
    }
}

// ---------------- GEMM1: h1 = x @ W1 ----------------
__global__ __launch_bounds__(256) void k_gemm1(const float* __restrict__ x,
                                               const float* __restrict__ W1,
                                               float* __restrict__ h1) {
    __shared__ float Ws[C1 * C2];   // 32 KB
    __shared__ float Xs[32 * C1];   //  8 KB
    int tid = threadIdx.x;
    int r0 = blockIdx.x * 32;
    for (int i = tid; i < C1 * C2; i += 256) Ws[i] = W1[i];
    for (int i = tid; i < 32 * C1; i += 256) {
        int row = r0 + (i >> 6);
        Xs[i] = (row < N_NODES) ? x[row * C1 + (i & 63)] : 0.0f;
    }
    __syncthreads();
    int c = tid & 127;
    int rg = tid >> 7;
    float acc[16];
#pragma unroll
    for (int r = 0; r < 16; ++r) acc[r] = 0.0f;
    for (int k = 0; k < C1; ++k) {
        float w = Ws[k * C2 + c];
#pragma unroll
        for (int r = 0; r < 16; ++r)
            acc[r] = fmaf(Xs[(rg * 16 + r) * C1 + k], w, acc[r]);
    }
#pragma unroll
    for (int r = 0; r < 16; ++r) {
        int row = r0 + rg * 16 + r;
        if (row < N_NODES) h1[row * C2 + c] = acc[r];
    }
}

// ---------------- pull aggregation layer 1 (128 ch, float2/lane), self-loop+bias fused ----------------
__global__ __launch_bounds__(256) void k_pull1(const int* __restrict__ rowptr,
                                               const int* __restrict__ csr,
                                               const float* __restrict__ h1,
                                               const float* __restrict__ dinv,
                                               const float* __restrict__ b1,
                                               float* __restrict__ agg1) {
    int node = blockIdx.x * 4 + (threadIdx.x >> 6);
    if (node >= N_NODES) return;
    int lane = threadIdx.x & 63;
    int start = rowptr[node], end = rowptr[node + 1];
    float dd = dinv[node];
    float2 h = *(const float2*)(h1 + node * C2 + lane * 2);
    float2 b = *(const float2*)(b1 + lane * 2);
    float2 acc;
    acc.x = fmaf(h.x, dd * dd, b.x);
    acc.y = fmaf(h.y, dd * dd, b.y);
    for (int j0 = start; j0 < end; j0 += 64) {
        int n = end - j0; if (n > 64) n = 64;
        int idx = 0;
        if (lane < n) idx = csr[j0 + lane];
        float ds = dinv[idx];
        for (int k = 0; k < n; ++k) {
            int s = __shfl(idx, k);
            float w = __shfl(ds, k) * dd;
            float2 v = *(const float2*)(h1 + s * C2 + lane * 2);
            acc.x = fmaf(v.x, w, acc.x);
            acc.y = fmaf(v.y, w, acc.y);
        }
    }
    *(float2*)(agg1 + node * C2 + lane * 2) = acc;
}

// ---------------- BN stats ----------------
__global__ __launch_bounds__(256) void k_stats(const float* __restrict__ agg1,
                                               float* __restrict__ stats) {
    __shared__ float ls[256], lq[256];
    int tid = threadIdx.x;
    int c = tid & 127, half = tid >> 7;
    float s = 0.0f, q = 0.0f;
    for (int row = blockIdx.x * 2 + half; row < N_NODES; row += gridDim.x * 2) {
        float v = agg1[row * C2 + c];
        s += v; q += v * v;
    }
    ls[tid] = s; lq[tid] = q;
    __syncthreads();
    if (tid < 128) {
        s = ls[tid] + ls[tid + 128];
        q = lq[tid] + lq[tid + 128];
        unsafeAtomicAdd(&stats[c], s);
        unsafeAtomicAdd(&stats[128 + c], q);
    }
}

__global__ void k_bnparam(const float* __restrict__ gamma, const float* __restrict__ beta,
                          float* __restrict__ stats) {
    int c = threadIdx.x;
    if (c < 128) {
        const float invN = 1.0f / (float)N_NODES;
        float mean = stats[c] * invN;
        float var = stats[128 + c] * invN - mean * mean;
        float sc = gamma[c] * rsqrtf(var + 1e-5f);
        stats[256 + c] = sc;
        stats[384 + c] = beta[c] - mean * sc;
    }
}

// ---------------- GEMM2: h2 = relu(bn(agg1)) @ W2 ----------------
__global__ __launch_bounds__(256) void k_gemm2(const float* __restrict__ agg1,
                                               const float* __restrict__ W2,
                                               const float* __restrict__ stats,
                                               float* __restrict__ h2) {
    __shared__ float Ws[C2 * C3];   // 32 KB
    __shared__ float As[32 * C2];   // 16 KB
    int tid = threadIdx.x;
    int r0 = blockIdx.x * 32;
    for (int i = tid; i < C2 * C3; i += 256) Ws[i] = W2[i];
    for (int i = tid; i < 32 * C2; i += 256) {
        int row = r0 + (i >> 7);
        int cc = i & 127;
        float v = 0.0f;
        if (row < N_NODES)
            v = fmaxf(fmaf(agg1[row * C2 + cc], stats[256 + cc], stats[384 + cc]), 0.0f);
        As[i] = v;
    }
    __syncthreads();
    int c = tid & 63;
    int rg = tid >> 6;
    float acc[8];
#pragma unroll
    for (int r = 0; r < 8; ++r) acc[r] = 0.0f;
    for (int k = 0; k < C2; ++k) {
        float w = Ws[k * C3 + c];
#pragma unroll
        for (int r = 0; r < 8; ++r)
            acc[r] = fmaf(As[(rg * 8 + r) * C2 + k], w, acc[r]);
    }
#pragma unroll
    for (int r = 0; r < 8; ++r) {
        int row = r0 + rg * 8 + r;
        if (row < N_NODES) h2[row * C3 + c] = acc[r];
    }
}

// ---------------- pull aggregation layer 2 (64 ch, 1 float/lane) ----------------
__global__ __launch_bounds__(256) void k_pull2(const int* __restrict__ rowptr,
                                               const int* __restrict__ csr,
                                               const float* __restrict__ h2,
                                               const float* __restrict__ dinv,
                                               const float* __restrict__ b2,
                                               float* __restrict__ out) {
    int node = blockIdx.x * 4 + (threadIdx.x >> 6);
    if (node >= N_NODES) return;
    int lane = threadIdx.x & 63;
    int start = rowptr[node], end = rowptr[node + 1];
    float dd = dinv[node];
    float h = h2[node * C3 + lane];
    float acc = fmaf(h, dd * dd, b2[lane]);
    for (int j0 = start; j0 < end; j0 += 64) {
        int n = end - j0; if (n > 64) n = 64;
        int idx = 0;
        if (lane < n) idx = csr[j0 + lane];
        float ds = dinv[idx];
        for (int k = 0; k < n; ++k) {
            int s = __shfl(idx, k);
            float w = __shfl(ds, k) * dd;
            acc = fmaf(h2[s * C3 + lane], w, acc);
        }
    }
    out[node * C3 + lane] = acc;
}

extern "C" void kernel_launch(void* const* d_in, const int* in_sizes, int n_in,
                              void* d_out, int out_size, void* d_ws, size_t ws_size,
                              hipStream_t stream) {
    const float* x     = (const float*)d_in[0];
    const int*   ei    = (const int*)d_in[1];
    const float* W1    = (const float*)d_in[2];
    const float* b1    = (const float*)d_in[3];
    const float* gamma = (const float*)d_in[4];
    const float* beta  = (const float*)d_in[5];
    const float* W2    = (const float*)d_in[6];
    const float* b2    = (const float*)d_in[7];
    float* out = (float*)d_out;

    int E = in_sizes[1] / 2;
    const int* src = ei;
    const int* dst = ei + E;

    // workspace layout (bytes):
    //   0         dinv    [50176 f]   200704
    //   200704    stats   [512 f]     2048
    //   202752    indeg   [50176 i]   200704
    //   403456    rowptr  [50176 i]   200704
    //   604160    cursor  [50176 i]   200704
    //   804864    csr_src [1.6M i]    6400000
    //   7204864   h1/h2   [50000*128] 25600000
    //   32804864  agg1    [50000*128] 25600000  -> end 58404864
    char* ws = (char*)d_ws;
    float* dinv   = (float*)ws;
    float* stats  = (float*)(ws + 200704);
    int*   indeg  = (int*)(ws + 202752);
    int*   rowptr = (int*)(ws + 403456);
    int*   cursor = (int*)(ws + 604160);
    int*   csr    = (int*)(ws + 804864);
    float* h1     = (float*)(ws + 7204864);
    float* agg1   = (float*)(ws + 32804864);
    float* h2     = h1;   // h1 dead after k_pull1

    const int nblk_nodes = (N_NODES + 255) / 256;
    const int nblk_rows  = (N_NODES + 31) / 32;
    const int nblk_edge  = (E + 255) / 256;
    const int nblk_pull  = (N_NODES + 3) / 4;

    k_zero<<<nblk_nodes, 256, 0, stream>>>(indeg, stats);
    k_deg<<<nblk_edge, 256, 0, stream>>>(dst, E, indeg);
    k_scan<<<1, SCAN_T, 0, stream>>>(indeg, dinv, rowptr, cursor);
    k_bucket<<<nblk_edge, 256, 0, stream>>>(src, dst, E, cursor, csr);

    k_gemm1<<<nblk_rows, 256, 0, stream>>>(x, W1, h1);
    k_pull1<<<nblk_pull, 256, 0, stream>>>(rowptr, csr, h1, dinv, b1, agg1);

    k_stats<<<256, 256, 0, stream>>>(agg1, stats);
    k_bnparam<<<1, 128, 0, stream>>>(gamma, beta, stats);

    k_gemm2<<<nblk_rows, 256, 0, stream>>>(agg1, W2, stats, h2);
    k_pull2<<<nblk_pull, 256, 0, stream>>>(rowptr, csr, h2, dinv, b2, out);
}

// Round 4
// 583.622 us; speedup vs baseline: 3.2894x; 1.2282x over previous
//
#include <hip/hip_runtime.h>

#define N_NODES 50000
#define C1 64    // in channels
#define C2 128   // hidden
#define C3 64    // latent / out

// ---------------- zero indeg + stats + total ----------------
__global__ void k_zero(int* __restrict__ indeg, float* __restrict__ stats,
                       int* __restrict__ total) {
    int i = blockIdx.x * blockDim.x + threadIdx.x;
    if (i < N_NODES) indeg[i] = 0;
    if (i < 512) stats[i] = 0.0f;
    if (i == 0) *total = 0;
}

// ---------------- in-degree count (int atomics) ----------------
__global__ void k_deg(const int* __restrict__ dst, int E, int* __restrict__ indeg) {
    int i = blockIdx.x * blockDim.x + threadIdx.x;
    if (i < E) atomicAdd(&indeg[dst[i]], 1);
}

// ---------------- segment allocation: wave-prefix + one atomic per wave ----------------
__global__ void k_alloc(const int* __restrict__ indeg, float* __restrict__ dinv,
                        int* __restrict__ rowstart, int* __restrict__ cursor,
                        int* __restrict__ total) {
    int i = blockIdx.x * blockDim.x + threadIdx.x;
    int lane = threadIdx.x & 63;
    int deg = (i < N_NODES) ? indeg[i] : 0;
    int pfx = deg;  // inclusive in-wave scan
#pragma unroll
    for (int off = 1; off < 64; off <<= 1) {
        int v = __shfl_up(pfx, off);
        if (lane >= off) pfx += v;
    }
    int wavetot = __shfl(pfx, 63);
    int base = 0;
    if (lane == 63) base = atomicAdd(total, wavetot);
    base = __shfl(base, 63);
    if (i < N_NODES) {
        int st = base + (pfx - deg);
        rowstart[i] = st;
        cursor[i] = st;
        dinv[i] = rsqrtf(1.0f + (float)deg);   // deg includes self-loop
    }
}

// ---------------- bucket edges into dst-CSR ----------------
__global__ void k_bucket(const int* __restrict__ src, const int* __restrict__ dst, int E,
                         int* __restrict__ cursor, int* __restrict__ csr) {
    int e = blockIdx.x * blockDim.x + threadIdx.x;
    if (e < E) {
        int d = dst[e];
        int pos = atomicAdd(&cursor[d], 1);
        csr[pos] = src[e];
    }
}

// ---------------- GEMM1: h1 = x @ W1 ----------------
__global__ __launch_bounds__(256) void k_gemm1(const float* __restrict__ x,
                                               const float* __restrict__ W1,
                                               float* __restrict__ h1) {
    __shared__ float Ws[C1 * C2];   // 32 KB
    __shared__ float Xs[32 * C1];   //  8 KB
    int tid = threadIdx.x;
    int r0 = blockIdx.x * 32;
    for (int i = tid; i < C1 * C2; i += 256) Ws[i] = W1[i];
    for (int i = tid; i < 32 * C1; i += 256) {
        int row = r0 + (i >> 6);
        Xs[i] = (row < N_NODES) ? x[row * C1 + (i & 63)] : 0.0f;
    }
    __syncthreads();
    int c = tid & 127;
    int rg = tid >> 7;
    float acc[16];
#pragma unroll
    for (int r = 0; r < 16; ++r) acc[r] = 0.0f;
    for (int k = 0; k < C1; ++k) {
        float w = Ws[k * C2 + c];
#pragma unroll
        for (int r = 0; r < 16; ++r)
            acc[r] = fmaf(Xs[(rg * 16 + r) * C1 + k], w, acc[r]);
    }
#pragma unroll
    for (int r = 0; r < 16; ++r) {
        int row = r0 + rg * 16 + r;
        if (row < N_NODES) h1[row * C2 + c] = acc[r];
    }
}

// ---------------- pull aggregation layer 1 (128 ch, float2/lane), self-loop+bias fused ----------------
__global__ __launch_bounds__(256) void k_pull1(const int* __restrict__ rowstart,
                                               const int* __restrict__ indeg,
                                               const int* __restrict__ csr,
                                               const float* __restrict__ h1,
                                               const float* __restrict__ dinv,
                                               const float* __restrict__ b1,
                                               float* __restrict__ agg1) {
    int node = blockIdx.x * 4 + (threadIdx.x >> 6);
    if (node >= N_NODES) return;
    int lane = threadIdx.x & 63;
    int start = rowstart[node], end = start + indeg[node];
    float dd = dinv[node];
    float2 h = *(const float2*)(h1 + node * C2 + lane * 2);
    float2 b = *(const float2*)(b1 + lane * 2);
    float2 acc;
    acc.x = fmaf(h.x, dd * dd, b.x);
    acc.y = fmaf(h.y, dd * dd, b.y);
    for (int j0 = start; j0 < end; j0 += 64) {
        int n = end - j0; if (n > 64) n = 64;
        int idx = 0;
        if (lane < n) idx = csr[j0 + lane];
        float ds = dinv[idx];
        for (int k = 0; k < n; ++k) {
            int s = __shfl(idx, k);
            float w = __shfl(ds, k) * dd;
            float2 v = *(const float2*)(h1 + s * C2 + lane * 2);
            acc.x = fmaf(v.x, w, acc.x);
            acc.y = fmaf(v.y, w, acc.y);
        }
    }
    *(float2*)(agg1 + node * C2 + lane * 2) = acc;
}

// ---------------- BN stats ----------------
__global__ __launch_bounds__(256) void k_stats(const float* __restrict__ agg1,
                                               float* __restrict__ stats) {
    __shared__ float ls[256], lq[256];
    int tid = threadIdx.x;
    int c = tid & 127, half = tid >> 7;
    float s = 0.0f, q = 0.0f;
    for (int row = blockIdx.x * 2 + half; row < N_NODES; row += gridDim.x * 2) {
        float v = agg1[row * C2 + c];
        s += v; q += v * v;
    }
    ls[tid] = s; lq[tid] = q;
    __syncthreads();
    if (tid < 128) {
        s = ls[tid] + ls[tid + 128];
        q = lq[tid] + lq[tid + 128];
        unsafeAtomicAdd(&stats[c], s);
        unsafeAtomicAdd(&stats[128 + c], q);
    }
}

__global__ void k_bnparam(const float* __restrict__ gamma, const float* __restrict__ beta,
                          float* __restrict__ stats) {
    int c = threadIdx.x;
    if (c < 128) {
        const float invN = 1.0f / (float)N_NODES;
        float mean = stats[c] * invN;
        float var = stats[128 + c] * invN - mean * mean;
        float sc = gamma[c] * rsqrtf(var + 1e-5f);
        stats[256 + c] = sc;
        stats[384 + c] = beta[c] - mean * sc;
    }
}

// ---------------- GEMM2: h2 = relu(bn(agg1)) @ W2 ----------------
__global__ __launch_bounds__(256) void k_gemm2(const float* __restrict__ agg1,
                                               const float* __restrict__ W2,
                                               const float* __restrict__ stats,
                                               float* __restrict__ h2) {
    __shared__ float Ws[C2 * C3];   // 32 KB
    __shared__ float As[32 * C2];   // 16 KB
    int tid = threadIdx.x;
    int r0 = blockIdx.x * 32;
    for (int i = tid; i < C2 * C3; i += 256) Ws[i] = W2[i];
    for (int i = tid; i < 32 * C2; i += 256) {
        int row = r0 + (i >> 7);
        int cc = i & 127;
        float v = 0.0f;
        if (row < N_NODES)
            v = fmaxf(fmaf(agg1[row * C2 + cc], stats[256 + cc], stats[384 + cc]), 0.0f);
        As[i] = v;
    }
    __syncthreads();
    int c = tid & 63;
    int rg = tid >> 6;
    float acc[8];
#pragma unroll
    for (int r = 0; r < 8; ++r) acc[r] = 0.0f;
    for (int k = 0; k < C2; ++k) {
        float w = Ws[k * C3 + c];
#pragma unroll
        for (int r = 0; r < 8; ++r)
            acc[r] = fmaf(As[(rg * 8 + r) * C2 + k], w, acc[r]);
    }
#pragma unroll
    for (int r = 0; r < 8; ++r) {
        int row = r0 + rg * 8 + r;
        if (row < N_NODES) h2[row * C3 + c] = acc[r];
    }
}

// ---------------- pull aggregation layer 2 (64 ch, 1 float/lane) ----------------
__global__ __launch_bounds__(256) void k_pull2(const int* __restrict__ rowstart,
                                               const int* __restrict__ indeg,
                                               const int* __restrict__ csr,
                                               const float* __restrict__ h2,
                                               const float* __restrict__ dinv,
                                               const float* __restrict__ b2,
                                               float* __restrict__ out) {
    int node = blockIdx.x * 4 + (threadIdx.x >> 6);
    if (node >= N_NODES) return;
    int lane = threadIdx.x & 63;
    int start = rowstart[node], end = start + indeg[node];
    float dd = dinv[node];
    float h = h2[node * C3 + lane];
    float acc = fmaf(h, dd * dd, b2[lane]);
    for (int j0 = start; j0 < end; j0 += 64) {
        int n = end - j0; if (n > 64) n = 64;
        int idx = 0;
        if (lane < n) idx = csr[j0 + lane];
        float ds = dinv[idx];
        for (int k = 0; k < n; ++k) {
            int s = __shfl(idx, k);
            float w = __shfl(ds, k) * dd;
            acc = fmaf(h2[s * C3 + lane], w, acc);
        }
    }
    out[node * C3 + lane] = acc;
}

extern "C" void kernel_launch(void* const* d_in, const int* in_sizes, int n_in,
                              void* d_out, int out_size, void* d_ws, size_t ws_size,
                              hipStream_t stream) {
    const float* x     = (const float*)d_in[0];
    const int*   ei    = (const int*)d_in[1];
    const float* W1    = (const float*)d_in[2];
    const float* b1    = (const float*)d_in[3];
    const float* gamma = (const float*)d_in[4];
    const float* beta  = (const float*)d_in[5];
    const float* W2    = (const float*)d_in[6];
    const float* b2    = (const float*)d_in[7];
    float* out = (float*)d_out;

    int E = in_sizes[1] / 2;
    const int* src = ei;
    const int* dst = ei + E;

    // workspace layout (bytes):
    //   0         dinv     [50176 f]   200704
    //   200704    stats    [512 f]     2048
    //   202752    total    [1 i]       (pad to 4096)
    //   206848    indeg    [50176 i]   200704
    //   407552    rowstart [50176 i]   200704
    //   608256    cursor   [50176 i]   200704
    //   808960    csr_src  [1.6M i]    6400000
    //   7208960   h1/h2    [50000*128] 25600000
    //   32808960  agg1     [50000*128] 25600000  -> end 58408960
    char* ws = (char*)d_ws;
    float* dinv     = (float*)ws;
    float* stats    = (float*)(ws + 200704);
    int*   total    = (int*)(ws + 202752);
    int*   indeg    = (int*)(ws + 206848);
    int*   rowstart = (int*)(ws + 407552);
    int*   cursor   = (int*)(ws + 608256);
    int*   csr      = (int*)(ws + 808960);
    float* h1       = (float*)(ws + 7208960);
    float* agg1     = (float*)(ws + 32808960);
    float* h2       = h1;   // h1 dead after k_pull1

    const int nblk_nodes = (N_NODES + 255) / 256;
    const int nblk_rows  = (N_NODES + 31) / 32;
    const int nblk_edge  = (E + 255) / 256;
    const int nblk_pull  = (N_NODES + 3) / 4;

    k_zero<<<nblk_nodes, 256, 0, stream>>>(indeg, stats, total);
    k_deg<<<nblk_edge, 256, 0, stream>>>(dst, E, indeg);
    k_alloc<<<nblk_nodes, 256, 0, stream>>>(indeg, dinv, rowstart, cursor, total);
    k_bucket<<<nblk_edge, 256, 0, stream>>>(src, dst, E, cursor, csr);

    k_gemm1<<<nblk_rows, 256, 0, stream>>>(x, W1, h1);
    k_pull1<<<nblk_pull, 256, 0, stream>>>(rowstart, indeg, csr, h1, dinv, b1, agg1);

    k_stats<<<256, 256, 0, stream>>>(agg1, stats);
    k_bnparam<<<1, 128, 0, stream>>>(gamma, beta, stats);

    k_gemm2<<<nblk_rows, 256, 0, stream>>>(agg1, W2, stats, h2);
    k_pull2<<<nblk_pull, 256, 0, stream>>>(rowstart, indeg, csr, h2, dinv, b2, out);
}